// Round 2
// baseline (309.402 us; speedup 1.0000x reference)
//
#include <hip/hip_runtime.h>
#include <hip/hip_bf16.h>
#include <math.h>

#define B_DIM 16
#define T_DIM 4096
#define D_DIM 512
#define R_DIM 256

#define TM 64           // rows (t) per block
#define BK 32           // k-tile
#define LDAP 40         // padded row pitch in bf16 (80 B, 16B-aligned)
#define LDBP 40

typedef __bf16 bf16x8 __attribute__((ext_vector_type(8)));
typedef float floatx4 __attribute__((ext_vector_type(4)));

// Replicate np.linspace(0, T-1, R).astype(int64) bit-exactly.
__device__ __forceinline__ int landmark_of(int r) {
    if (r >= 255) return 4095;
    const double step = 4095.0 / 255.0;
    return (int)((double)r * step);   // trunc toward zero == astype(int64)
}

__device__ __forceinline__ void split_bf16(float x, __bf16& h, __bf16& l) {
    h = (__bf16)x;
    l = (__bf16)(x - (float)h);
}

// ---- prep: normalized landmark rows of z, split into hi/lo bf16 ----
__global__ void nystrom_prep_kernel(const float* __restrict__ z,
                                    __bf16* __restrict__ Khi, __bf16* __restrict__ Klo) {
    int blk = blockIdx.x;
    int b = blk >> 8;
    int r = blk & 255;
    int lane = threadIdx.x;            // 64 threads
    int lm = landmark_of(r);
    const float* src = z + ((size_t)b * T_DIM + lm) * D_DIM + lane * 8;
    float4 v0 = ((const float4*)src)[0];
    float4 v1 = ((const float4*)src)[1];
    float ss = v0.x*v0.x + v0.y*v0.y + v0.z*v0.z + v0.w*v0.w
             + v1.x*v1.x + v1.y*v1.y + v1.z*v1.z + v1.w*v1.w;
    #pragma unroll
    for (int off = 1; off < 64; off <<= 1) ss += __shfl_xor(ss, off, 64);
    float inv = 1.0f / fmaxf(sqrtf(ss), 1e-12f);
    float q[8] = {v0.x*inv, v0.y*inv, v0.z*inv, v0.w*inv,
                  v1.x*inv, v1.y*inv, v1.z*inv, v1.w*inv};
    bf16x8 oh, ol;
    #pragma unroll
    for (int j = 0; j < 8; j++) { __bf16 h, l; split_bf16(q[j], h, l); oh[j] = h; ol[j] = l; }
    size_t dst = ((size_t)b * R_DIM + r) * D_DIM + lane * 8;
    *(bf16x8*)(Khi + dst) = oh;
    *(bf16x8*)(Klo + dst) = ol;
}

// ---- main: split-bf16 GEMM (z @ Kn^T) + norm + polynomial + mask/decay + row-normalize ----
__global__ __launch_bounds__(256, 2)
void nystrom_main_kernel(const float* __restrict__ z,
                         const __bf16* __restrict__ Khi, const __bf16* __restrict__ Klo,
                         const float* __restrict__ gw, const float* __restrict__ ta,
                         float* __restrict__ out) {
    __shared__ __attribute__((aligned(16))) __bf16 Ash[TM * LDAP];     // 5120 B
    __shared__ __attribute__((aligned(16))) __bf16 Asl[TM * LDAP];
    __shared__ __attribute__((aligned(16))) __bf16 Bsh[R_DIM * LDBP];  // 20480 B
    __shared__ __attribute__((aligned(16))) __bf16 Bsl[R_DIM * LDBP];
    __shared__ float red[256];
    __shared__ float rnorm[TM];
    __shared__ float rspart[4][TM];
    __shared__ float rinv[TM];
    __shared__ int   lmtab[R_DIM];
    __shared__ float elmtab[R_DIM];

    const int tid  = threadIdx.x;
    const int b    = blockIdx.y;
    const int t0   = blockIdx.x * TM;
    const int lane = tid & 63;
    const int wv   = tid >> 6;
    const int quad = lane >> 4;
    const int ln   = lane & 15;

    // --- scalars (recomputed per thread; trivial) ---
    float g0 = gw[0], g1 = gw[1], g2 = gw[2];
    float gm = fmaxf(g0, fmaxf(g1, g2));
    float e0 = expf(g0 - gm), e1 = expf(g1 - gm), e2 = expf(g2 - gm);
    float esum = e0 + e1 + e2;
    float al0 = e0 / esum, al1 = e1 / esum, al2 = e2 / esum;
    float ax = ta[0];
    float a_td = (ax > 20.f) ? ax : log1pf(expf(ax));

    if (tid < R_DIM) {
        int lm = landmark_of(tid);
        lmtab[tid] = lm;
        elmtab[tid] = expf(a_td * (float)lm * (1.0f / 4096.0f));
    }

    // staging maps
    const int srowA = tid >> 2;          // 0..63, 4 lanes per row
    const int scolA = (tid & 3) * 8;     // 0,8,16,24
    const float*  zrow = z + ((size_t)b * T_DIM + (t0 + srowA)) * D_DIM + scolA;
    const size_t  kboff = (size_t)b * R_DIM * D_DIM;
    const __bf16* Kbh = Khi + kboff;
    const __bf16* Kbl = Klo + kboff;

    floatx4 acc[4][4];
    #pragma unroll
    for (int i = 0; i < 4; i++)
        #pragma unroll
        for (int j = 0; j < 4; j++) acc[i][j] = (floatx4){0.f, 0.f, 0.f, 0.f};
    float ssq = 0.0f;

    for (int kt = 0; kt < D_DIM; kt += BK) {
        // --- stage A: 64x32 fp32 -> (hi,lo) bf16; accumulate sum-of-squares ---
        float4 a0 = *(const float4*)(zrow + kt + 0);
        float4 a1 = *(const float4*)(zrow + kt + 4);
        float av[8] = {a0.x, a0.y, a0.z, a0.w, a1.x, a1.y, a1.z, a1.w};
        #pragma unroll
        for (int j = 0; j < 8; j++) ssq += av[j] * av[j];
        bf16x8 ph, pl;
        #pragma unroll
        for (int j = 0; j < 8; j++) { __bf16 h, l; split_bf16(av[j], h, l); ph[j] = h; pl[j] = l; }
        *(bf16x8*)&Ash[srowA * LDAP + scolA] = ph;
        *(bf16x8*)&Asl[srowA * LDAP + scolA] = pl;
        // --- stage B: 256x32 hi/lo ---
        {
            const __bf16* bph = Kbh + (size_t)tid * D_DIM + kt;
            const __bf16* bpl = Kbl + (size_t)tid * D_DIM + kt;
            uint4 h0 = ((const uint4*)bph)[0], h1 = ((const uint4*)bph)[1];
            uint4 h2 = ((const uint4*)bph)[2], h3 = ((const uint4*)bph)[3];
            uint4 l0 = ((const uint4*)bpl)[0], l1 = ((const uint4*)bpl)[1];
            uint4 l2 = ((const uint4*)bpl)[2], l3 = ((const uint4*)bpl)[3];
            uint4* dh = (uint4*)&Bsh[tid * LDBP];
            uint4* dl = (uint4*)&Bsl[tid * LDBP];
            dh[0] = h0; dh[1] = h1; // wait: rows are LDBP=40 bf16 = 80 B = 5 uint4 pitch
            // (pitch 80B is a multiple of 16B so uint4 indexing below is valid)
            ((uint4*)((char*)&Bsh[0] + tid * 80))[0] = h0;
            ((uint4*)((char*)&Bsh[0] + tid * 80))[1] = h1;
            ((uint4*)((char*)&Bsh[0] + tid * 80))[2] = h2;
            ((uint4*)((char*)&Bsh[0] + tid * 80))[3] = h3;
            ((uint4*)((char*)&Bsl[0] + tid * 80))[0] = l0;
            ((uint4*)((char*)&Bsl[0] + tid * 80))[1] = l1;
            ((uint4*)((char*)&Bsl[0] + tid * 80))[2] = l2;
            ((uint4*)((char*)&Bsl[0] + tid * 80))[3] = l3;
        }
        __syncthreads();
        // --- MFMA: one k-step of 32, 3-pass split ---
        {
            int koff = quad * 8;
            bf16x8 afh[4], afl[4], bfh[4], bfl[4];
            #pragma unroll
            for (int mi = 0; mi < 4; mi++) {
                afh[mi] = *(const bf16x8*)&Ash[(mi * 16 + ln) * LDAP + koff];
                afl[mi] = *(const bf16x8*)&Asl[(mi * 16 + ln) * LDAP + koff];
            }
            #pragma unroll
            for (int ni = 0; ni < 4; ni++) {
                bfh[ni] = *(const bf16x8*)&Bsh[(wv * 64 + ni * 16 + ln) * LDBP + koff];
                bfl[ni] = *(const bf16x8*)&Bsl[(wv * 64 + ni * 16 + ln) * LDBP + koff];
            }
            #pragma unroll
            for (int mi = 0; mi < 4; mi++)
                #pragma unroll
                for (int ni = 0; ni < 4; ni++) {
                    acc[mi][ni] = __builtin_amdgcn_mfma_f32_16x16x32_bf16(
                        afh[mi], bfh[ni], acc[mi][ni], 0, 0, 0);
                    acc[mi][ni] = __builtin_amdgcn_mfma_f32_16x16x32_bf16(
                        afh[mi], bfl[ni], acc[mi][ni], 0, 0, 0);
                    acc[mi][ni] = __builtin_amdgcn_mfma_f32_16x16x32_bf16(
                        afl[mi], bfh[ni], acc[mi][ni], 0, 0, 0);
                }
        }
        __syncthreads();
    }

    // --- row norms: 4 partials per row ---
    red[tid] = ssq;
    __syncthreads();
    if (tid < TM) {
        float s = red[tid*4] + red[tid*4+1] + red[tid*4+2] + red[tid*4+3];
        rnorm[tid] = 1.0f / fmaxf(sqrtf(s), 1e-12f);
    }
    __syncthreads();

    // per-thread landmark columns
    int   lm_r[4];
    float elm_r[4];
    #pragma unroll
    for (int ni = 0; ni < 4; ni++) {
        int r = wv * 64 + ni * 16 + ln;
        lm_r[ni]  = lmtab[r];
        elm_r[ni] = elmtab[r];
    }

    // --- polynomial + mask + decay; row-sum reduce ---
    #pragma unroll
    for (int mi = 0; mi < 4; mi++) {
        #pragma unroll
        for (int reg = 0; reg < 4; reg++) {
            int row = mi * 16 + quad * 4 + reg;
            int t = t0 + row;
            float rn = rnorm[row];
            float e_t = expf(-a_td * (float)t * (1.0f / 4096.0f));
            float s = 0.f;
            #pragma unroll
            for (int ni = 0; ni < 4; ni++) {
                float phi = 0.f;
                if (lm_r[ni] < t) {
                    float c  = acc[mi][ni][reg] * rn;
                    float c2 = c * c;
                    float P1 = 0.5f * (1.f + c);
                    float P2 = 0.5f * (3.f * c2 - 1.f);
                    float P3 = 0.5f * (5.f * c2 * c - 3.f * c);
                    float p  = al0 * P1 + al1 * P2 + al2 * P3;
                    phi = p * e_t * elm_r[ni];
                }
                acc[mi][ni][reg] = phi;
                s += phi;
            }
            #pragma unroll
            for (int off = 1; off < 16; off <<= 1) s += __shfl_xor(s, off, 64);
            if (ln == 0) rspart[wv][row] = s;
        }
    }
    __syncthreads();
    if (tid < TM) {
        float rs = rspart[0][tid] + rspart[1][tid] + rspart[2][tid] + rspart[3][tid];
        rinv[tid] = 1.0f / fmaxf(rs, 1e-6f);
    }
    __syncthreads();

    // --- store Phi + ones column ---
    float* ob = out + ((size_t)b * T_DIM + t0) * 257;
    #pragma unroll
    for (int mi = 0; mi < 4; mi++) {
        #pragma unroll
        for (int reg = 0; reg < 4; reg++) {
            int row = mi * 16 + quad * 4 + reg;
            float inv = rinv[row];
            #pragma unroll
            for (int ni = 0; ni < 4; ni++) {
                int r = wv * 64 + ni * 16 + ln;
                ob[(size_t)row * 257 + r] = acc[mi][ni][reg] * inv;
            }
        }
    }
    if (tid < TM) ob[(size_t)tid * 257 + 256] = 1.0f;
}

extern "C" void kernel_launch(void* const* d_in, const int* in_sizes, int n_in,
                              void* d_out, int out_size, void* d_ws, size_t ws_size,
                              hipStream_t stream) {
    const float* z  = (const float*)d_in[0];
    const float* gw = (const float*)d_in[1];
    const float* ta = (const float*)d_in[2];
    float* out = (float*)d_out;
    __bf16* Khi = (__bf16*)d_ws;                                   // 4 MiB
    __bf16* Klo = (__bf16*)((char*)d_ws + (size_t)B_DIM * R_DIM * D_DIM * 2); // +4 MiB

    nystrom_prep_kernel<<<dim3(B_DIM * R_DIM), 64, 0, stream>>>(z, Khi, Klo);
    nystrom_main_kernel<<<dim3(T_DIM / TM, B_DIM), 256, 0, stream>>>(z, Khi, Klo, gw, ta, out);
}

// Round 3
// 252.244 us; speedup vs baseline: 1.2266x; 1.2266x over previous
//
#include <hip/hip_runtime.h>
#include <hip/hip_bf16.h>
#include <math.h>

#define B_DIM 16
#define T_DIM 4096
#define D_DIM 512
#define R_DIM 256

#define TM 128          // rows (t) per block
#define BK 32           // k-tile
#define LDP 40          // LDS row pitch in bf16 (80 B, 16B-aligned)
#define NKCH (D_DIM/BK) // 16 k-chunks in blocked B layout

typedef __bf16 bf16x8 __attribute__((ext_vector_type(8)));
typedef float floatx4 __attribute__((ext_vector_type(4)));

// Replicate np.linspace(0, T-1, R).astype(int64) bit-exactly.
__device__ __forceinline__ int landmark_of(int r) {
    if (r >= 255) return 4095;
    const double step = 4095.0 / 255.0;
    return (int)((double)r * step);   // trunc toward zero == astype(int64)
}

__device__ __forceinline__ void split_bf16(float x, __bf16& h, __bf16& l) {
    h = (__bf16)x;
    l = (__bf16)(x - (float)h);
}

// ---- prep: normalized landmark rows of z, split hi/lo, written in blocked
// layout [b][kchunk 0..15][row 0..255][32 cols] so main-kernel B staging is
// one contiguous 16 KB chunk per iteration (fully coalesced). ----
__global__ void nystrom_prep_kernel(const float* __restrict__ z,
                                    __bf16* __restrict__ Khi, __bf16* __restrict__ Klo) {
    int blk = blockIdx.x;
    int b = blk >> 8;
    int r = blk & 255;
    int lane = threadIdx.x;            // 64 threads
    int lm = landmark_of(r);
    const float* src = z + ((size_t)b * T_DIM + lm) * D_DIM + lane * 8;
    float4 v0 = ((const float4*)src)[0];
    float4 v1 = ((const float4*)src)[1];
    float ss = v0.x*v0.x + v0.y*v0.y + v0.z*v0.z + v0.w*v0.w
             + v1.x*v1.x + v1.y*v1.y + v1.z*v1.z + v1.w*v1.w;
    #pragma unroll
    for (int off = 1; off < 64; off <<= 1) ss += __shfl_xor(ss, off, 64);
    float inv = 1.0f / fmaxf(sqrtf(ss), 1e-12f);
    float q[8] = {v0.x*inv, v0.y*inv, v0.z*inv, v0.w*inv,
                  v1.x*inv, v1.y*inv, v1.z*inv, v1.w*inv};
    bf16x8 oh, ol;
    #pragma unroll
    for (int j = 0; j < 8; j++) { __bf16 h, l; split_bf16(q[j], h, l); oh[j] = h; ol[j] = l; }
    // lane covers cols lane*8..lane*8+7 -> kchunk = lane>>2, in-chunk off = (lane&3)*8
    size_t dst = (((size_t)b * NKCH + (lane >> 2)) * R_DIM + r) * BK + (size_t)(lane & 3) * 8;
    *(bf16x8*)(Khi + dst) = oh;
    *(bf16x8*)(Klo + dst) = ol;
}

// ---- main: split-bf16 GEMM (z @ Kn^T) + norm + polynomial + mask/decay + row-normalize ----
__global__ __launch_bounds__(256, 2)
void nystrom_main_kernel(const float* __restrict__ z,
                         const __bf16* __restrict__ Khi, const __bf16* __restrict__ Klo,
                         const float* __restrict__ gw, const float* __restrict__ ta,
                         float* __restrict__ out) {
    // Tile buffers (K-loop) aliased with epilogue scratch (strictly after last barrier).
    __shared__ __attribute__((aligned(16))) char smem[61440];
    __shared__ int   lmtab[R_DIM];
    __shared__ float elmtab[R_DIM];

    __bf16* Ash = (__bf16*)(smem);            // 128*40*2 = 10240 B
    __bf16* Asl = (__bf16*)(smem + 10240);
    __bf16* Bsh = (__bf16*)(smem + 20480);    // 256*40*2 = 20480 B
    __bf16* Bsl = (__bf16*)(smem + 40960);
    float* red    = (float*)(smem);           // 1024 B   (epilogue alias)
    float* rnormp = (float*)(smem + 1024);    // 512 B
    float* rinvp  = (float*)(smem + 1536);    // 512 B
    float* rspart = (float*)(smem + 2048);    // 4*128*4 = 2048 B

    const int tid  = threadIdx.x;
    const int b    = blockIdx.y;
    const int t0   = blockIdx.x * TM;
    const int lane = tid & 63;
    const int wv   = tid >> 6;
    const int quad = lane >> 4;
    const int ln   = lane & 15;

    // --- scalars (recomputed per thread; trivial) ---
    float g0 = gw[0], g1 = gw[1], g2 = gw[2];
    float gm = fmaxf(g0, fmaxf(g1, g2));
    float e0 = expf(g0 - gm), e1 = expf(g1 - gm), e2 = expf(g2 - gm);
    float esum = e0 + e1 + e2;
    float al0 = e0 / esum, al1 = e1 / esum, al2 = e2 / esum;
    float ax = ta[0];
    float a_td = (ax > 20.f) ? ax : log1pf(expf(ax));

    {
        int lm = landmark_of(tid);
        lmtab[tid] = lm;
        elmtab[tid] = expf(a_td * (float)lm * (1.0f / 4096.0f));
    }

    // staging maps: A = 2 lanes per row (16 cols each); B = 1 row per lane (32 cols)
    const int srowA = tid >> 1;
    const int scolA = (tid & 1) * 16;
    const float* zrow = z + ((size_t)b * T_DIM + (t0 + srowA)) * D_DIM + scolA;
    const size_t bbase = (size_t)b * NKCH * R_DIM * BK;   // blocked-layout batch base

    floatx4 acc[8][4];
    #pragma unroll
    for (int i = 0; i < 8; i++)
        #pragma unroll
        for (int j = 0; j < 4; j++) acc[i][j] = (floatx4){0.f, 0.f, 0.f, 0.f};
    float ssq = 0.0f;

    // ---- prefetch tile 0 into registers ----
    float4 a0, a1, a2, a3;
    uint4 h0, h1, h2, h3, l0, l1, l2, l3;
    {
        const float4* ap = (const float4*)(zrow);
        a0 = ap[0]; a1 = ap[1]; a2 = ap[2]; a3 = ap[3];
        const uint4* ph = (const uint4*)(Khi + bbase + (size_t)tid * BK);
        const uint4* pl = (const uint4*)(Klo + bbase + (size_t)tid * BK);
        h0 = ph[0]; h1 = ph[1]; h2 = ph[2]; h3 = ph[3];
        l0 = pl[0]; l1 = pl[1]; l2 = pl[2]; l3 = pl[3];
    }

    #pragma unroll 1
    for (int kt = 0; kt < D_DIM; kt += BK) {
        // --- consume regs: convert A, accumulate ssq, write LDS ---
        float av[16] = {a0.x,a0.y,a0.z,a0.w, a1.x,a1.y,a1.z,a1.w,
                        a2.x,a2.y,a2.z,a2.w, a3.x,a3.y,a3.z,a3.w};
        #pragma unroll
        for (int j = 0; j < 16; j++) ssq += av[j] * av[j];
        bf16x8 ph0, pl0, ph1, pl1;
        #pragma unroll
        for (int j = 0; j < 8; j++) { __bf16 h, l; split_bf16(av[j],   h, l); ph0[j]=h; pl0[j]=l; }
        #pragma unroll
        for (int j = 0; j < 8; j++) { __bf16 h, l; split_bf16(av[8+j], h, l); ph1[j]=h; pl1[j]=l; }
        *(bf16x8*)&Ash[srowA * LDP + scolA]     = ph0;
        *(bf16x8*)&Ash[srowA * LDP + scolA + 8] = ph1;
        *(bf16x8*)&Asl[srowA * LDP + scolA]     = pl0;
        *(bf16x8*)&Asl[srowA * LDP + scolA + 8] = pl1;
        {
            uint4* dh = (uint4*)((char*)Bsh + tid * (LDP * 2));
            uint4* dl = (uint4*)((char*)Bsl + tid * (LDP * 2));
            dh[0] = h0; dh[1] = h1; dh[2] = h2; dh[3] = h3;
            dl[0] = l0; dl[1] = l1; dl[2] = l2; dl[3] = l3;
        }
        __syncthreads();
        // --- prefetch next tile (in flight during MFMA phase) ---
        if (kt + BK < D_DIM) {
            const float4* ap = (const float4*)(zrow + kt + BK);
            a0 = ap[0]; a1 = ap[1]; a2 = ap[2]; a3 = ap[3];
            size_t coff = bbase + (size_t)((kt >> 5) + 1) * R_DIM * BK + (size_t)tid * BK;
            const uint4* ph = (const uint4*)(Khi + coff);
            const uint4* pl = (const uint4*)(Klo + coff);
            h0 = ph[0]; h1 = ph[1]; h2 = ph[2]; h3 = ph[3];
            l0 = pl[0]; l1 = pl[1]; l2 = pl[2]; l3 = pl[3];
        }
        // --- MFMA: one k-step of 32, 3-pass split ---
        {
            const int koff = quad * 8;
            bf16x8 bfh[4], bfl[4];
            #pragma unroll
            for (int ni = 0; ni < 4; ni++) {
                int rrow = wv * 64 + ni * 16 + ln;
                bfh[ni] = *(const bf16x8*)&Bsh[rrow * LDP + koff];
                bfl[ni] = *(const bf16x8*)&Bsl[rrow * LDP + koff];
            }
            #pragma unroll
            for (int mi = 0; mi < 8; mi++) {
                bf16x8 afh = *(const bf16x8*)&Ash[(mi * 16 + ln) * LDP + koff];
                bf16x8 afl = *(const bf16x8*)&Asl[(mi * 16 + ln) * LDP + koff];
                #pragma unroll
                for (int ni = 0; ni < 4; ni++) {
                    acc[mi][ni] = __builtin_amdgcn_mfma_f32_16x16x32_bf16(
                        afh, bfh[ni], acc[mi][ni], 0, 0, 0);
                    acc[mi][ni] = __builtin_amdgcn_mfma_f32_16x16x32_bf16(
                        afh, bfl[ni], acc[mi][ni], 0, 0, 0);
                    acc[mi][ni] = __builtin_amdgcn_mfma_f32_16x16x32_bf16(
                        afl, bfh[ni], acc[mi][ni], 0, 0, 0);
                }
            }
        }
        __syncthreads();
    }

    // --- row norms: 2 partials per row (epilogue scratch aliases tile LDS) ---
    red[tid] = ssq;
    __syncthreads();
    if (tid < TM) {
        float s = red[tid * 2] + red[tid * 2 + 1];
        rnormp[tid] = 1.0f / fmaxf(sqrtf(s), 1e-12f);
    }
    __syncthreads();

    // per-thread landmark columns
    int   lm_r[4];
    float elm_r[4];
    #pragma unroll
    for (int ni = 0; ni < 4; ni++) {
        int r = wv * 64 + ni * 16 + ln;
        lm_r[ni]  = lmtab[r];
        elm_r[ni] = elmtab[r];
    }

    // --- polynomial + mask + decay; row-sum reduce ---
    #pragma unroll
    for (int mi = 0; mi < 8; mi++) {
        #pragma unroll
        for (int reg = 0; reg < 4; reg++) {
            int row = mi * 16 + quad * 4 + reg;
            int t = t0 + row;
            float rn = rnormp[row];
            float e_t = expf(-a_td * (float)t * (1.0f / 4096.0f));
            float s = 0.f;
            #pragma unroll
            for (int ni = 0; ni < 4; ni++) {
                float phi = 0.f;
                if (lm_r[ni] < t) {
                    float c  = acc[mi][ni][reg] * rn;
                    float c2 = c * c;
                    float P1 = 0.5f * (1.f + c);
                    float P2 = 0.5f * (3.f * c2 - 1.f);
                    float P3 = 0.5f * (5.f * c2 * c - 3.f * c);
                    float p  = al0 * P1 + al1 * P2 + al2 * P3;
                    phi = p * e_t * elm_r[ni];
                }
                acc[mi][ni][reg] = phi;
                s += phi;
            }
            #pragma unroll
            for (int off = 1; off < 16; off <<= 1) s += __shfl_xor(s, off, 64);
            if (ln == 0) rspart[wv * TM + row] = s;
        }
    }
    __syncthreads();
    if (tid < TM) {
        float rs = rspart[0 * TM + tid] + rspart[1 * TM + tid]
                 + rspart[2 * TM + tid] + rspart[3 * TM + tid];
        rinvp[tid] = 1.0f / fmaxf(rs, 1e-6f);
    }
    __syncthreads();

    // --- store Phi + ones column ---
    float* ob = out + ((size_t)b * T_DIM + t0) * 257;
    #pragma unroll
    for (int mi = 0; mi < 8; mi++) {
        #pragma unroll
        for (int reg = 0; reg < 4; reg++) {
            int row = mi * 16 + quad * 4 + reg;
            float inv = rinvp[row];
            #pragma unroll
            for (int ni = 0; ni < 4; ni++) {
                int r = wv * 64 + ni * 16 + ln;
                ob[(size_t)row * 257 + r] = acc[mi][ni][reg] * inv;
            }
        }
    }
    if (tid < TM) ob[(size_t)tid * 257 + 256] = 1.0f;
}

extern "C" void kernel_launch(void* const* d_in, const int* in_sizes, int n_in,
                              void* d_out, int out_size, void* d_ws, size_t ws_size,
                              hipStream_t stream) {
    const float* z  = (const float*)d_in[0];
    const float* gw = (const float*)d_in[1];
    const float* ta = (const float*)d_in[2];
    float* out = (float*)d_out;
    __bf16* Khi = (__bf16*)d_ws;                                               // 4 MiB
    __bf16* Klo = (__bf16*)((char*)d_ws + (size_t)B_DIM * R_DIM * D_DIM * 2);  // +4 MiB

    nystrom_prep_kernel<<<dim3(B_DIM * R_DIM), 64, 0, stream>>>(z, Khi, Klo);
    nystrom_main_kernel<<<dim3(T_DIM / TM, B_DIM), 256, 0, stream>>>(z, Khi, Klo, gw, ta, out);
}